// Round 4
// baseline (654.026 us; speedup 1.0000x reference)
//
#include <hip/hip_runtime.h>
#include <math.h>

// FCM mutual-kNN attention mixing. N=8192, D=256, K=16.
//   K0 init:  zero stats/nbad
//   K1 prep:  feats->bf16, row sqnorms, exact fixed-point sum/sumsq of sq
//   K2 gemm:  bf16 MFMA F F^T, fused per-row threshold candidate select (no panel)
//   K2b fallback: full-rescan repair of rows with cnt<17 or cnt>CAP (expected none)
//   K3 refine: fp64 exact d2+dot over <=256 candidates -> exact top-17
//   K4 out:   mutual mask + sparse softmax + mix + normalize
#define NPTS 8192
#define DIM  256
#define NSLOT 17
#define CAP  256
#define ZTH  (-2.20f)
typedef unsigned int uint;
typedef unsigned short ushort;
typedef unsigned long long ull;
typedef __attribute__((ext_vector_type(8))) short bf16x8;
typedef __attribute__((ext_vector_type(4))) float f32x4;

__device__ __forceinline__ ushort f2bf(float f) {
    uint x = __float_as_uint(f);
    return (ushort)((x + 0x7fffu + ((x >> 16) & 1u)) >> 16);
}

// ---------------- K0: zero stats ----------------
__global__ void init_kernel(ull* stats, uint* nbad) {
    if (threadIdx.x == 0) { stats[0] = 0ull; stats[1] = 0ull; *nbad = 0u; }
}

// ---------------- K1: bf16 copy + sqnorms + exact stats ----------------
__global__ void prep_kernel(const float* __restrict__ feats, ushort* __restrict__ fb,
                            float* __restrict__ sq, ull* __restrict__ stats) {
    const int row  = blockIdx.x * 4 + (threadIdx.x >> 6);
    const int lane = threadIdx.x & 63;
    const float4 v = *reinterpret_cast<const float4*>(feats + (size_t)row * DIM + lane * 4);
    ushort4 b; b.x = f2bf(v.x); b.y = f2bf(v.y); b.z = f2bf(v.z); b.w = f2bf(v.w);
    *reinterpret_cast<ushort4*>(fb + (size_t)row * DIM + lane * 4) = b;
    float p = v.x * v.x + v.y * v.y + v.z * v.z + v.w * v.w;
#pragma unroll
    for (int off = 32; off > 0; off >>= 1) p += __shfl_down(p, off, 64);
    if (lane == 0) {
        sq[row] = p;
        atomicAdd(&stats[0], (ull)llrintf(p * 1048576.f));         // Q20
        atomicAdd(&stats[1], (ull)llrintf(p * p * 16384.f));       // Q14
    }
}

// ---------------- K2: MFMA GEMM + fused threshold select ----------------
// 512 thr = 8 waves; block owns 32 rows; J-tiles of 256 cols; KC=64 double-buffered.
__global__ __launch_bounds__(512, 1) void gemm_select_kernel(
    const ushort* __restrict__ fb, const float* __restrict__ sq,
    const ull* __restrict__ stats, int* __restrict__ cand, int* __restrict__ cnt_g,
    int* __restrict__ badlist, uint* __restrict__ nbad) {
    __shared__ ushort Bs[2][256 * 64];   // 64 KB, [buf][col][k] swizzled
    __shared__ int    cbuf[32][CAP];     // 32 KB
    __shared__ float  Ts[32], sqi_s[32];
    __shared__ int    cnt[32];

    const int tid = threadIdx.x;
    const int w   = tid >> 6;
    const int l   = tid & 63;
    const int l15 = l & 15, lg = l >> 4;
    const int row0 = blockIdx.x * 32;

    if (tid < 32) {
        const double s0 = (double)stats[0], s1 = (double)stats[1];
        const float mu  = (float)(s0 / (1048576.0 * NPTS));
        const float var = fmaxf(1.0f, (float)(s1 / (16384.0 * NPTS)) - mu * mu);
        const float qi  = sq[row0 + tid];
        sqi_s[tid] = qi;
        Ts[tid]    = qi + mu + ZTH * sqrtf(var + 4.f * qi);
        cnt[tid]   = 0;
    }

    // A fragments resident: a[mf][ks]
    bf16x8 a[2][8];
#pragma unroll
    for (int mf = 0; mf < 2; ++mf) {
        const ushort* ap = fb + (size_t)(row0 + mf * 16 + l15) * DIM + lg * 8;
#pragma unroll
        for (int ks = 0; ks < 8; ++ks)
            a[mf][ks] = *reinterpret_cast<const bf16x8*>(ap + ks * 32);
    }

    // prologue: stage chunk 0 into Bs[0]
    {
        const int kslot = tid & 7;
#pragma unroll
        for (int p = 0; p < 4; ++p) {
            const int col = (tid >> 3) + p * 64;
            const bf16x8 v = *reinterpret_cast<const bf16x8*>(
                fb + (size_t)col * DIM + kslot * 8);
            const int byt = col * 128 + ((kslot * 16) ^ ((col & 7) << 4));
            *reinterpret_cast<bf16x8*>(reinterpret_cast<char*>(Bs[0]) + byt) = v;
        }
    }

    f32x4 acc[2][2];
#pragma unroll
    for (int mf = 0; mf < 2; ++mf)
#pragma unroll
        for (int cf = 0; cf < 2; ++cf) acc[mf][cf] = (f32x4){0.f, 0.f, 0.f, 0.f};

    const int NCH = (NPTS / 256) * 4;    // 128 chunks
    for (int ch = 0; ch < NCH; ++ch) {
        __syncthreads();                 // stage(ch) visible; compute(ch-1) done
        // issue global loads for chunk ch+1
        bf16x8 st[4];
        const bool do_stage = (ch + 1 < NCH);
        if (do_stage) {
            const int c = ch + 1;
            const int Jn = (c >> 2) * 256, kcn = (c & 3) * 64;
            const int kslot = tid & 7;
#pragma unroll
            for (int p = 0; p < 4; ++p) {
                const int col = (tid >> 3) + p * 64;
                st[p] = *reinterpret_cast<const bf16x8*>(
                    fb + (size_t)(Jn + col) * DIM + kcn + kslot * 8);
            }
        }
        // compute chunk ch from Bs[ch&1]
        {
            const char* Bb = reinterpret_cast<const char*>(Bs[ch & 1]);
            const int ksb = (ch & 3) * 2;
#pragma unroll
            for (int kk = 0; kk < 2; ++kk) {
                bf16x8 b0, b1;
                {
                    const int col = w * 32 + l15;
                    b0 = *reinterpret_cast<const bf16x8*>(
                        Bb + col * 128 + ((kk * 64 + lg * 16) ^ ((col & 7) << 4)));
                }
                {
                    const int col = w * 32 + 16 + l15;
                    b1 = *reinterpret_cast<const bf16x8*>(
                        Bb + col * 128 + ((kk * 64 + lg * 16) ^ ((col & 7) << 4)));
                }
                acc[0][0] = __builtin_amdgcn_mfma_f32_16x16x32_bf16(a[0][ksb + kk], b0, acc[0][0], 0, 0, 0);
                acc[0][1] = __builtin_amdgcn_mfma_f32_16x16x32_bf16(a[0][ksb + kk], b1, acc[0][1], 0, 0, 0);
                acc[1][0] = __builtin_amdgcn_mfma_f32_16x16x32_bf16(a[1][ksb + kk], b0, acc[1][0], 0, 0, 0);
                acc[1][1] = __builtin_amdgcn_mfma_f32_16x16x32_bf16(a[1][ksb + kk], b1, acc[1][1], 0, 0, 0);
            }
        }
        // write staged chunk ch+1 into Bs[(ch+1)&1]
        if (do_stage) {
            const int kslot = tid & 7;
            char* Bn = reinterpret_cast<char*>(Bs[(ch + 1) & 1]);
#pragma unroll
            for (int p = 0; p < 4; ++p) {
                const int col = (tid >> 3) + p * 64;
                const int byt = col * 128 + ((kslot * 16) ^ ((col & 7) << 4));
                *reinterpret_cast<bf16x8*>(Bn + byt) = st[p];
            }
        }
        // J-tile epilogue: threshold select
        if ((ch & 3) == 3) {
            const int J = (ch >> 2) * 256;
            float sqc[2];
            sqc[0] = sq[J + w * 32 + l15];
            sqc[1] = sq[J + w * 32 + 16 + l15];
#pragma unroll
            for (int mf = 0; mf < 2; ++mf)
#pragma unroll
                for (int cf = 0; cf < 2; ++cf)
#pragma unroll
                    for (int r = 0; r < 4; ++r) {
                        const int row = mf * 16 + lg * 4 + r;
                        const float key = sqi_s[row] + sqc[cf] - 2.f * acc[mf][cf][r];
                        if (key < Ts[row]) {
                            const int pos = atomicAdd(&cnt[row], 1);
                            if (pos < CAP) cbuf[row][pos] = J + w * 32 + cf * 16 + l15;
                        }
                    }
#pragma unroll
            for (int mf = 0; mf < 2; ++mf)
#pragma unroll
                for (int cf = 0; cf < 2; ++cf) acc[mf][cf] = (f32x4){0.f, 0.f, 0.f, 0.f};
        }
    }
    __syncthreads();
    if (tid < 32) {
        const int c = cnt[tid];
        cnt_g[row0 + tid] = min(c, CAP);
        if (c < NSLOT || c > CAP) {
            const uint pos = atomicAdd(nbad, 1u);
            badlist[pos] = row0 + tid;
        }
    }
    for (int s = tid; s < 32 * CAP; s += 512) {
        const int r = s >> 8, sl = s & (CAP - 1);
        cand[(size_t)(row0 + r) * CAP + sl] = (sl < min(cnt[r], CAP)) ? cbuf[r][sl] : -1;
    }
}

// ---------------- K2b: fallback full rescan for bad rows ----------------
__global__ void fallback_kernel(const float* __restrict__ feats, const float* __restrict__ sq,
                                const int* __restrict__ badlist, const uint* __restrict__ nbad,
                                int* __restrict__ cand, int* __restrict__ cnt_g) {
    __shared__ float fi_s[DIM];
    __shared__ float keys[NPTS];         // 32 KB
    __shared__ float rkey[4];
    __shared__ int   rid[4];
    const int t = threadIdx.x;
    const uint nb = *nbad;
    for (uint bi = blockIdx.x; bi < nb; bi += gridDim.x) {
        const int row = badlist[bi];
        fi_s[t] = feats[(size_t)row * DIM + t];
        __syncthreads();
        const float sqi = sq[row];
        for (int p = 0; p < NPTS / 256; ++p) {
            const int jj = p * 256 + t;
            const float* fj = feats + (size_t)jj * DIM;
            float d = 0.f;
            for (int dq = 0; dq < DIM / 4; ++dq) {
                const float4 b4 = *reinterpret_cast<const float4*>(fj + dq * 4);
                const float4 a4 = *reinterpret_cast<const float4*>(&fi_s[dq * 4]);
                d = fmaf(a4.x, b4.x, fmaf(a4.y, b4.y, fmaf(a4.z, b4.z, fmaf(a4.w, b4.w, d))));
            }
            keys[jj] = sqi + sq[jj] - 2.f * d;
        }
        __syncthreads();
        for (int r = 0; r < 64; ++r) {
            float bk = INFINITY; int bj = 0x7fffffff;
            for (int p = 0; p < NPTS / 256; ++p) {
                const int jj = p * 256 + t;
                const float kv = keys[jj];
                if (kv < bk || (kv == bk && jj < bj)) { bk = kv; bj = jj; }
            }
#pragma unroll
            for (int off = 1; off <= 32; off <<= 1) {
                const float ok = __shfl_xor(bk, off, 64);
                const int   oj = __shfl_xor(bj, off, 64);
                if (ok < bk || (ok == bk && oj < bj)) { bk = ok; bj = oj; }
            }
            if ((t & 63) == 0) { rkey[t >> 6] = bk; rid[t >> 6] = bj; }
            __syncthreads();
            float fk = rkey[0]; int fj2 = rid[0];
#pragma unroll
            for (int q = 1; q < 4; ++q)
                if (rkey[q] < fk || (rkey[q] == fk && rid[q] < fj2)) { fk = rkey[q]; fj2 = rid[q]; }
            if (t == 0) { cand[(size_t)row * CAP + r] = fj2; keys[fj2] = INFINITY; }
            __syncthreads();
        }
        if (t == 0) cnt_g[row] = 64;
        __syncthreads();
    }
}

// ---------------- K3: fp64 refine -> exact top-17 ----------------
__global__ void refine_kernel(const float* __restrict__ feats, const int* __restrict__ cand,
                              const int* __restrict__ cnt_g,
                              int* __restrict__ fidx, float* __restrict__ fscr) {
    __shared__ float  fi_s[DIM];
    __shared__ double rdd[4];
    __shared__ int    ridx[4];
    __shared__ float  rdot[4];
    const int t = threadIdx.x, i = blockIdx.x;
    fi_s[t] = feats[(size_t)i * DIM + t];
    __syncthreads();
    const int nc = cnt_g[i];
    int j = (t < nc) ? cand[(size_t)i * CAP + t] : -1;
    double dd = 1e300, dot = 0.0;
    if (j >= 0) {
        const float* fj = feats + (size_t)j * DIM;
        dd = 0.0;
        for (int dq = 0; dq < DIM / 4; ++dq) {
            const float4 b4 = *reinterpret_cast<const float4*>(fj + dq * 4);
            const float4 a4 = *reinterpret_cast<const float4*>(&fi_s[dq * 4]);
            const double dx = (double)a4.x - b4.x, dy = (double)a4.y - b4.y;
            const double dz = (double)a4.z - b4.z, dw = (double)a4.w - b4.w;
            dd  += dx * dx + dy * dy + dz * dz + dw * dw;
            dot += (double)a4.x * b4.x + (double)a4.y * b4.y +
                   (double)a4.z * b4.z + (double)a4.w * b4.w;
        }
    } else j = 0x7fffffff;
    float sc = (float)dot;
    const int lane = t & 63, wv = t >> 6;
    for (int r = 0; r < NSLOT; ++r) {
        double mdd = dd; int mj = j; float ms = sc;
#pragma unroll
        for (int off = 1; off <= 32; off <<= 1) {
            const double odd = __shfl_xor(mdd, off, 64);
            const int    oj  = __shfl_xor(mj, off, 64);
            const float  os  = __shfl_xor(ms, off, 64);
            if (odd < mdd || (odd == mdd && oj < mj)) { mdd = odd; mj = oj; ms = os; }
        }
        if (lane == 0) { rdd[wv] = mdd; ridx[wv] = mj; rdot[wv] = ms; }
        __syncthreads();
        double bdd = rdd[0]; int bj = ridx[0]; float bs = rdot[0];
#pragma unroll
        for (int q = 1; q < 4; ++q)
            if (rdd[q] < bdd || (rdd[q] == bdd && ridx[q] < bj)) { bdd = rdd[q]; bj = ridx[q]; bs = rdot[q]; }
        if (t == 0) { fidx[(size_t)i * NSLOT + r] = bj; fscr[(size_t)i * NSLOT + r] = bs; }
        if (j == bj) dd = 1e300;
        __syncthreads();
    }
}

// ---------------- K4: mutual mask + sparse softmax + mix + normalize ----------------
__global__ void fcm_out_kernel(const float* __restrict__ feats,
                               const int* __restrict__ knn_idx,
                               const float* __restrict__ knn_scr,
                               float* __restrict__ out) {
    const int w    = threadIdx.x >> 6;
    const int lane = threadIdx.x & 63;
    const int i    = blockIdx.x * 4 + w;

    int jt = -1; float st = 0.f; bool valid = false;
    if (lane < NSLOT) {
        jt = knn_idx[(size_t)i * NSLOT + lane];
        st = knn_scr[(size_t)i * NSLOT + lane];
        if (jt != i) {
            const int* nb = knn_idx + (size_t)jt * NSLOT;
#pragma unroll
            for (int s = 0; s < NSLOT; ++s) valid |= (nb[s] == i);
        }
    }
    float val = valid ? st : -INFINITY;
#pragma unroll
    for (int off = 32; off > 0; off >>= 1) val = fmaxf(val, __shfl_xor(val, off, 64));
    const float m  = fmaxf(1.0f, val);
    const float wt = valid ? expf(st - m) : 0.f;
    float ws = wt;
#pragma unroll
    for (int off = 32; off > 0; off >>= 1) ws += __shfl_xor(ws, off, 64);
    const float wdiag = expf(1.0f - m);
    const float inv   = 1.0f / (ws + wdiag);

    const float4 fi = *reinterpret_cast<const float4*>(feats + (size_t)i * DIM + lane * 4);
    float ax = fi.x * wdiag, ay = fi.y * wdiag, az = fi.z * wdiag, aw = fi.w * wdiag;
    for (int t = 0; t < NSLOT; ++t) {
        const float wtt = __shfl(wt, t, 64);
        const int   jj  = __shfl(jt, t, 64);
        if (wtt > 0.f) {
            const float4 fj = *reinterpret_cast<const float4*>(feats + (size_t)jj * DIM + lane * 4);
            ax = fmaf(wtt, fj.x, ax); ay = fmaf(wtt, fj.y, ay);
            az = fmaf(wtt, fj.z, az); aw = fmaf(wtt, fj.w, aw);
        }
    }
    const float ox = fmaf(ax, inv, fi.x), oy = fmaf(ay, inv, fi.y);
    const float oz = fmaf(az, inv, fi.z), ow = fmaf(aw, inv, fi.w);
    float nn = ox * ox + oy * oy + oz * oz + ow * ow;
#pragma unroll
    for (int off = 32; off > 0; off >>= 1) nn += __shfl_xor(nn, off, 64);
    const float scl = 1.0f / fmaxf(sqrtf(nn), 1e-12f);
    float4 o; o.x = ox * scl; o.y = oy * scl; o.z = oz * scl; o.w = ow * scl;
    *reinterpret_cast<float4*>(out + (size_t)i * DIM + lane * 4) = o;
}

extern "C" void kernel_launch(void* const* d_in, const int* in_sizes, int n_in,
                              void* d_out, int out_size, void* d_ws, size_t ws_size,
                              hipStream_t stream) {
    (void)in_sizes; (void)n_in; (void)out_size; (void)ws_size;
    const float* feats = (const float*)d_in[0];
    float* out = (float*)d_out;
    char* ws = (char*)d_ws;
    size_t off = 0;
    float* sq      = (float*)(ws + off); off += NPTS * 4;                 // 32 KB
    ull*   stats   = (ull*)  (ws + off); off += 128;
    uint*  nbad    = (uint*) ((char*)stats + 16);
    ushort* fb     = (ushort*)(ws + off); off += (size_t)NPTS * DIM * 2;  // 4 MB
    int*   cand    = (int*)  (ws + off); off += (size_t)NPTS * CAP * 4;   // 8 MB
    int*   cnt_g   = (int*)  (ws + off); off += NPTS * 4;
    int*   badlist = (int*)  (ws + off); off += NPTS * 4;
    int*   fidx    = (int*)  (ws + off); off += NPTS * NSLOT * 4;
    float* fscr    = (float*)(ws + off); off += NPTS * NSLOT * 4;

    init_kernel<<<1, 64, 0, stream>>>(stats, nbad);
    prep_kernel<<<NPTS / 4, 256, 0, stream>>>(feats, fb, sq, stats);
    gemm_select_kernel<<<NPTS / 32, 512, 0, stream>>>(fb, sq, stats, cand, cnt_g, badlist, nbad);
    fallback_kernel<<<64, 256, 0, stream>>>(feats, sq, badlist, nbad, cand, cnt_g);
    refine_kernel<<<NPTS, 256, 0, stream>>>(feats, cand, cnt_g, fidx, fscr);
    fcm_out_kernel<<<NPTS / 4, 256, 0, stream>>>(feats, fidx, fscr, out);
}

// Round 5
// 519.945 us; speedup vs baseline: 1.2579x; 1.2579x over previous
//
#include <hip/hip_runtime.h>
#include <math.h>

// FCM mutual-kNN attention mixing. N=8192, D=256, K=16.
//   K0 init:  zero stats
//   K1 prep:  feats->bf16, row sqnorms, exact fixed-point stats, zero cnt_g
//   K2 gemm:  bf16 MFMA F F^T, TM=64 rows x J-half 4096, fused threshold select
//   K2b fallback: detect + full-rescan repair of bad rows (expected none)
//   K3 refine: fp64 exact d2+dot over <=256 candidates -> exact top-17
//   K4 out:   mutual mask + sparse softmax + mix + normalize
#define NPTS 8192
#define DIM  256
#define NSLOT 17
#define CAP  256
#define LCAP 128
#define ZTH  (-2.45f)
typedef unsigned int uint;
typedef unsigned short ushort;
typedef unsigned long long ull;
typedef __attribute__((ext_vector_type(8))) short bf16x8;
typedef __attribute__((ext_vector_type(4))) float f32x4;

__device__ __forceinline__ ushort f2bf(float f) {
    uint x = __float_as_uint(f);
    return (ushort)((x + 0x7fffu + ((x >> 16) & 1u)) >> 16);
}

// ---------------- K0 ----------------
__global__ void init_kernel(ull* stats) {
    if (threadIdx.x == 0) { stats[0] = 0ull; stats[1] = 0ull; }
}

// ---------------- K1: bf16 copy + sqnorms + stats + cnt_g=0 ----------------
__global__ void prep_kernel(const float* __restrict__ feats, ushort* __restrict__ fb,
                            float* __restrict__ sq, ull* __restrict__ stats,
                            int* __restrict__ cnt_g) {
    const int row  = blockIdx.x * 4 + (threadIdx.x >> 6);
    const int lane = threadIdx.x & 63;
    const float4 v = *reinterpret_cast<const float4*>(feats + (size_t)row * DIM + lane * 4);
    ushort4 b; b.x = f2bf(v.x); b.y = f2bf(v.y); b.z = f2bf(v.z); b.w = f2bf(v.w);
    *reinterpret_cast<ushort4*>(fb + (size_t)row * DIM + lane * 4) = b;
    float p = v.x * v.x + v.y * v.y + v.z * v.z + v.w * v.w;
#pragma unroll
    for (int off = 32; off > 0; off >>= 1) p += __shfl_down(p, off, 64);
    if (lane == 0) {
        sq[row] = p;
        cnt_g[row] = 0;
        atomicAdd(&stats[0], (ull)llrintf(p * 1048576.f));     // Q20
        atomicAdd(&stats[1], (ull)llrintf(p * p * 16384.f));   // Q14
    }
}

// ---------------- K2: MFMA GEMM + fused threshold select ----------------
// 512 thr = 8 waves. Block: 64 rows (A resident in regs) x one 4096-col J-half.
// rowblk = bid>>1, half = bid&1  => XCD (bid%8) serves a single half (L2 locality).
__global__ __launch_bounds__(512, 1) void gemm_select_kernel(
    const ushort* __restrict__ fb, const float* __restrict__ sq,
    const ull* __restrict__ stats, int* __restrict__ cand, int* __restrict__ cnt_g) {
    __shared__ ushort Bs[2][256 * 64];   // 2 x 32 KB [buf][col][k] swizzled
    __shared__ int    cbuf[64][LCAP];    // 32 KB
    __shared__ float  Ts[64], sqi_s[64];
    __shared__ int    cnt[64];
    __shared__ int    base_s[64], n_s[64];

    const int tid = threadIdx.x;
    const int w   = tid >> 6;
    const int l   = tid & 63;
    const int l15 = l & 15, lg = l >> 4;
    const int row0  = (blockIdx.x >> 1) * 64;
    const int Jbase = (blockIdx.x & 1) * 4096;

    if (tid < 64) {
        const double s0 = (double)stats[0], s1 = (double)stats[1];
        const float mu  = (float)(s0 / (1048576.0 * NPTS));
        const float var = fmaxf(1.0f, (float)(s1 / (16384.0 * NPTS)) - mu * mu);
        const float qi  = sq[row0 + tid];
        sqi_s[tid] = qi;
        Ts[tid]    = qi + mu + ZTH * sqrtf(var + 4.f * qi);
        cnt[tid]   = 0;
    }

    // A resident: a[mf][ks] = F[row0+mf*16+l15][ks*32+lg*8 .. +7]
    bf16x8 a[4][8];
#pragma unroll
    for (int mf = 0; mf < 4; ++mf) {
        const ushort* ap = fb + (size_t)(row0 + mf * 16 + l15) * DIM + lg * 8;
#pragma unroll
        for (int ks = 0; ks < 8; ++ks)
            a[mf][ks] = *reinterpret_cast<const bf16x8*>(ap + ks * 32);
    }

    // prologue: stage chunk 0 (tile 0, kc 0) into Bs[0]
    {
        const int kslot = tid & 7;
#pragma unroll
        for (int p = 0; p < 4; ++p) {
            const int col = (tid >> 3) + p * 64;
            const bf16x8 v = *reinterpret_cast<const bf16x8*>(
                fb + (size_t)(Jbase + col) * DIM + kslot * 8);
            const int byt = col * 128 + ((kslot * 16) ^ ((col & 7) << 4));
            *reinterpret_cast<bf16x8*>(reinterpret_cast<char*>(Bs[0]) + byt) = v;
        }
    }

    f32x4 acc[4][2];
#pragma unroll
    for (int mf = 0; mf < 4; ++mf) { acc[mf][0] = (f32x4){0,0,0,0}; acc[mf][1] = (f32x4){0,0,0,0}; }

    for (int tile = 0; tile < 16; ++tile) {
#pragma unroll
        for (int kc4 = 0; kc4 < 4; ++kc4) {
            __syncthreads();             // Bs[kc4&1] staged; other buffer free
            // issue loads for next chunk
            bf16x8 st[4];
            const int cnext = tile * 4 + kc4 + 1;
            const bool do_stage = (cnext < 64);
            if (do_stage) {
                const int Jn  = Jbase + (cnext >> 2) * 256;
                const int kcn = ((kc4 + 1) & 3) * 64;
                const int kslot = tid & 7;
#pragma unroll
                for (int p = 0; p < 4; ++p) {
                    const int col = (tid >> 3) + p * 64;
                    st[p] = *reinterpret_cast<const bf16x8*>(
                        fb + (size_t)(Jn + col) * DIM + kcn + kslot * 8);
                }
            }
            // compute chunk from Bs[kc4&1]
            {
                const char* Bb = reinterpret_cast<const char*>(Bs[kc4 & 1]);
#pragma unroll
                for (int kk = 0; kk < 2; ++kk) {
                    const int col0 = w * 32 + l15;
                    const int col1 = w * 32 + 16 + l15;
                    const bf16x8 b0 = *reinterpret_cast<const bf16x8*>(
                        Bb + col0 * 128 + ((kk * 64 + lg * 16) ^ ((col0 & 7) << 4)));
                    const bf16x8 b1 = *reinterpret_cast<const bf16x8*>(
                        Bb + col1 * 128 + ((kk * 64 + lg * 16) ^ ((col1 & 7) << 4)));
#pragma unroll
                    for (int mf = 0; mf < 4; ++mf) {
                        acc[mf][0] = __builtin_amdgcn_mfma_f32_16x16x32_bf16(
                            a[mf][kc4 * 2 + kk], b0, acc[mf][0], 0, 0, 0);
                        acc[mf][1] = __builtin_amdgcn_mfma_f32_16x16x32_bf16(
                            a[mf][kc4 * 2 + kk], b1, acc[mf][1], 0, 0, 0);
                    }
                }
            }
            // write staged chunk into the other buffer
            if (do_stage) {
                const int kslot = tid & 7;
                char* Bn = reinterpret_cast<char*>(Bs[(kc4 + 1) & 1]);
#pragma unroll
                for (int p = 0; p < 4; ++p) {
                    const int col = (tid >> 3) + p * 64;
                    const int byt = col * 128 + ((kslot * 16) ^ ((col & 7) << 4));
                    *reinterpret_cast<bf16x8*>(Bn + byt) = st[p];
                }
            }
        }
        // ---- per-J-tile epilogue: threshold select ----
        const int Jt = Jbase + tile * 256;
        const float sqc0 = sq[Jt + w * 32 + l15];
        const float sqc1 = sq[Jt + w * 32 + 16 + l15];
#pragma unroll
        for (int mf = 0; mf < 4; ++mf)
#pragma unroll
            for (int r = 0; r < 4; ++r) {
                const int row = mf * 16 + lg * 4 + r;
                const float si = sqi_s[row], tt = Ts[row];
                const float k0 = si + sqc0 - 2.f * acc[mf][0][r];
                if (k0 < tt) {
                    const int pos = atomicAdd(&cnt[row], 1);
                    if (pos < LCAP) cbuf[row][pos] = Jt + w * 32 + l15;
                }
                const float k1 = si + sqc1 - 2.f * acc[mf][1][r];
                if (k1 < tt) {
                    const int pos = atomicAdd(&cnt[row], 1);
                    if (pos < LCAP) cbuf[row][pos] = Jt + w * 32 + 16 + l15;
                }
            }
#pragma unroll
        for (int mf = 0; mf < 4; ++mf) { acc[mf][0] = (f32x4){0,0,0,0}; acc[mf][1] = (f32x4){0,0,0,0}; }
    }
    __syncthreads();
    if (tid < 64) {
        const int local = cnt[tid];
        const int n = min(local, LCAP);
        const int add = (local > LCAP) ? (n + (1 << 20)) : n;   // poison on overflow
        base_s[tid] = atomicAdd(&cnt_g[row0 + tid], add);
        n_s[tid] = n;
    }
    __syncthreads();
    for (int s = tid; s < 64 * LCAP; s += 512) {
        const int r = s >> 7, k2 = s & (LCAP - 1);
        if (k2 < n_s[r]) {
            const int b = base_s[r] + k2;
            if (b < CAP) cand[(size_t)(row0 + r) * CAP + b] = cbuf[r][k2];
        }
    }
}

// ---------------- K2b: detect + repair bad rows (expected none) ----------------
__global__ void fallback_kernel(const float* __restrict__ feats, const float* __restrict__ sq,
                                int* __restrict__ cand, int* __restrict__ cnt_g) {
    __shared__ float fi_s[DIM];
    __shared__ float keys[NPTS];         // 32 KB
    __shared__ float rkey[4];
    __shared__ int   rid[4];
    const int t = threadIdx.x;
    for (int row = blockIdx.x; row < NPTS; row += gridDim.x) {
        const int v = cnt_g[row];
        if (v >= NSLOT && v <= CAP) continue;
        fi_s[t] = feats[(size_t)row * DIM + t];
        __syncthreads();
        const float sqi = sq[row];
        for (int p = 0; p < NPTS / 256; ++p) {
            const int jj = p * 256 + t;
            const float* fj = feats + (size_t)jj * DIM;
            float d = 0.f;
            for (int dq = 0; dq < DIM / 4; ++dq) {
                const float4 b4 = *reinterpret_cast<const float4*>(fj + dq * 4);
                const float4 a4 = *reinterpret_cast<const float4*>(&fi_s[dq * 4]);
                d = fmaf(a4.x, b4.x, fmaf(a4.y, b4.y, fmaf(a4.z, b4.z, fmaf(a4.w, b4.w, d))));
            }
            keys[jj] = sqi + sq[jj] - 2.f * d;
        }
        __syncthreads();
        for (int r = 0; r < 64; ++r) {
            float bk = INFINITY; int bj = 0x7fffffff;
            for (int p = 0; p < NPTS / 256; ++p) {
                const int jj = p * 256 + t;
                const float kv = keys[jj];
                if (kv < bk || (kv == bk && jj < bj)) { bk = kv; bj = jj; }
            }
#pragma unroll
            for (int off = 1; off <= 32; off <<= 1) {
                const float ok = __shfl_xor(bk, off, 64);
                const int   oj = __shfl_xor(bj, off, 64);
                if (ok < bk || (ok == bk && oj < bj)) { bk = ok; bj = oj; }
            }
            if ((t & 63) == 0) { rkey[t >> 6] = bk; rid[t >> 6] = bj; }
            __syncthreads();
            float fk = rkey[0]; int fj2 = rid[0];
#pragma unroll
            for (int q = 1; q < 4; ++q)
                if (rkey[q] < fk || (rkey[q] == fk && rid[q] < fj2)) { fk = rkey[q]; fj2 = rid[q]; }
            if (t == 0) { cand[(size_t)row * CAP + r] = fj2; keys[fj2] = INFINITY; }
            __syncthreads();
        }
        if (t == 0) cnt_g[row] = 64;
        __syncthreads();
    }
}

// ---------------- K3: fp64 refine -> exact top-17 ----------------
__global__ void refine_kernel(const float* __restrict__ feats, const int* __restrict__ cand,
                              const int* __restrict__ cnt_g,
                              int* __restrict__ fidx, float* __restrict__ fscr) {
    __shared__ float  fi_s[DIM];
    __shared__ double rdd[4];
    __shared__ int    ridx[4];
    __shared__ float  rdot[4];
    const int t = threadIdx.x, i = blockIdx.x;
    fi_s[t] = feats[(size_t)i * DIM + t];
    __syncthreads();
    const int nc = min(cnt_g[i], CAP);
    int j = (t < nc) ? cand[(size_t)i * CAP + t] : -1;
    double dd = 1e300, dot = 0.0;
    if (j >= 0) {
        const float* fj = feats + (size_t)j * DIM;
        dd = 0.0;
        for (int dq = 0; dq < DIM / 4; ++dq) {
            const float4 b4 = *reinterpret_cast<const float4*>(fj + dq * 4);
            const float4 a4 = *reinterpret_cast<const float4*>(&fi_s[dq * 4]);
            const double dx = (double)a4.x - b4.x, dy = (double)a4.y - b4.y;
            const double dz = (double)a4.z - b4.z, dw = (double)a4.w - b4.w;
            dd  += dx * dx + dy * dy + dz * dz + dw * dw;
            dot += (double)a4.x * b4.x + (double)a4.y * b4.y +
                   (double)a4.z * b4.z + (double)a4.w * b4.w;
        }
    } else j = 0x7fffffff;
    float sc = (float)dot;
    const int lane = t & 63, wv = t >> 6;
    for (int r = 0; r < NSLOT; ++r) {
        double mdd = dd; int mj = j; float ms = sc;
#pragma unroll
        for (int off = 1; off <= 32; off <<= 1) {
            const double odd = __shfl_xor(mdd, off, 64);
            const int    oj  = __shfl_xor(mj, off, 64);
            const float  os  = __shfl_xor(ms, off, 64);
            if (odd < mdd || (odd == mdd && oj < mj)) { mdd = odd; mj = oj; ms = os; }
        }
        if (lane == 0) { rdd[wv] = mdd; ridx[wv] = mj; rdot[wv] = ms; }
        __syncthreads();
        double bdd = rdd[0]; int bj = ridx[0]; float bs = rdot[0];
#pragma unroll
        for (int q = 1; q < 4; ++q)
            if (rdd[q] < bdd || (rdd[q] == bdd && ridx[q] < bj)) { bdd = rdd[q]; bj = ridx[q]; bs = rdot[q]; }
        if (t == 0) { fidx[(size_t)i * NSLOT + r] = bj; fscr[(size_t)i * NSLOT + r] = bs; }
        if (j == bj) dd = 1e300;
        __syncthreads();
    }
}

// ---------------- K4: mutual mask + sparse softmax + mix + normalize ----------------
__global__ void fcm_out_kernel(const float* __restrict__ feats,
                               const int* __restrict__ knn_idx,
                               const float* __restrict__ knn_scr,
                               float* __restrict__ out) {
    const int w    = threadIdx.x >> 6;
    const int lane = threadIdx.x & 63;
    const int i    = blockIdx.x * 4 + w;

    int jt = -1; float st = 0.f; bool valid = false;
    if (lane < NSLOT) {
        jt = knn_idx[(size_t)i * NSLOT + lane];
        st = knn_scr[(size_t)i * NSLOT + lane];
        if (jt != i) {
            const int* nb = knn_idx + (size_t)jt * NSLOT;
#pragma unroll
            for (int s = 0; s < NSLOT; ++s) valid |= (nb[s] == i);
        }
    }
    float val = valid ? st : -INFINITY;
#pragma unroll
    for (int off = 32; off > 0; off >>= 1) val = fmaxf(val, __shfl_xor(val, off, 64));
    const float m  = fmaxf(1.0f, val);
    const float wt = valid ? expf(st - m) : 0.f;
    float ws = wt;
#pragma unroll
    for (int off = 32; off > 0; off >>= 1) ws += __shfl_xor(ws, off, 64);
    const float wdiag = expf(1.0f - m);
    const float inv   = 1.0f / (ws + wdiag);

    const float4 fi = *reinterpret_cast<const float4*>(feats + (size_t)i * DIM + lane * 4);
    float ax = fi.x * wdiag, ay = fi.y * wdiag, az = fi.z * wdiag, aw = fi.w * wdiag;
    for (int t = 0; t < NSLOT; ++t) {
        const float wtt = __shfl(wt, t, 64);
        const int   jj  = __shfl(jt, t, 64);
        if (wtt > 0.f) {
            const float4 fj = *reinterpret_cast<const float4*>(feats + (size_t)jj * DIM + lane * 4);
            ax = fmaf(wtt, fj.x, ax); ay = fmaf(wtt, fj.y, ay);
            az = fmaf(wtt, fj.z, az); aw = fmaf(wtt, fj.w, aw);
        }
    }
    const float ox = fmaf(ax, inv, fi.x), oy = fmaf(ay, inv, fi.y);
    const float oz = fmaf(az, inv, fi.z), ow = fmaf(aw, inv, fi.w);
    float nn = ox * ox + oy * oy + oz * oz + ow * ow;
#pragma unroll
    for (int off = 32; off > 0; off >>= 1) nn += __shfl_xor(nn, off, 64);
    const float scl = 1.0f / fmaxf(sqrtf(nn), 1e-12f);
    float4 o; o.x = ox * scl; o.y = oy * scl; o.z = oz * scl; o.w = ow * scl;
    *reinterpret_cast<float4*>(out + (size_t)i * DIM + lane * 4) = o;
}

extern "C" void kernel_launch(void* const* d_in, const int* in_sizes, int n_in,
                              void* d_out, int out_size, void* d_ws, size_t ws_size,
                              hipStream_t stream) {
    (void)in_sizes; (void)n_in; (void)out_size; (void)ws_size;
    const float* feats = (const float*)d_in[0];
    float* out = (float*)d_out;
    char* ws = (char*)d_ws;
    size_t off = 0;
    float*  sq    = (float*) (ws + off); off += NPTS * 4;                 // 32 KB
    ull*    stats = (ull*)   (ws + off); off += 128;
    ushort* fb    = (ushort*)(ws + off); off += (size_t)NPTS * DIM * 2;   // 4 MB
    int*    cand  = (int*)   (ws + off); off += (size_t)NPTS * CAP * 4;   // 8 MB
    int*    cnt_g = (int*)   (ws + off); off += NPTS * 4;
    int*    fidx  = (int*)   (ws + off); off += NPTS * NSLOT * 4;
    float*  fscr  = (float*) (ws + off); off += NPTS * NSLOT * 4;

    init_kernel<<<1, 64, 0, stream>>>(stats);
    prep_kernel<<<NPTS / 4, 256, 0, stream>>>(feats, fb, sq, stats, cnt_g);
    gemm_select_kernel<<<NPTS / 32, 512, 0, stream>>>(fb, sq, stats, cand, cnt_g);
    fallback_kernel<<<64, 256, 0, stream>>>(feats, sq, cand, cnt_g);
    refine_kernel<<<NPTS, 256, 0, stream>>>(feats, cand, cnt_g, fidx, fscr);
    fcm_out_kernel<<<NPTS / 4, 256, 0, stream>>>(feats, fidx, fscr, out);
}

// Round 6
// 207.595 us; speedup vs baseline: 3.1505x; 2.5046x over previous
//
#include <hip/hip_runtime.h>
#include <math.h>

// FCM mutual-kNN attention mixing. N=8192, D=256, K=16.
//   K1 prep:   feats->bf16, row sqnorms, zero cnt_g  (no atomics)
//   K1b stats: deterministic reduction of sq -> mu/var (single block)
//   K2 gemm:   bf16 MFMA F F^T, TM=64 x J-half 4096, fused threshold select
//   K2b fallback: detect + full-rescan repair of bad rows (expected none)
//   K3 refine: fp64 exact d2+dot, 4 lanes/candidate -> exact top-17
//   K4 out:    mutual mask + sparse softmax + mix + normalize
#define NPTS 8192
#define DIM  256
#define NSLOT 17
#define CAP  256
#define LCAP 128
#define ZTH  (-2.45f)
typedef unsigned int uint;
typedef unsigned short ushort;
typedef unsigned long long ull;
typedef __attribute__((ext_vector_type(8))) short bf16x8;
typedef __attribute__((ext_vector_type(4))) float f32x4;

__device__ __forceinline__ ushort f2bf(float f) {
    uint x = __float_as_uint(f);
    return (ushort)((x + 0x7fffu + ((x >> 16) & 1u)) >> 16);
}

// ---------------- K1: bf16 copy + sqnorms + cnt_g=0 ----------------
__global__ void prep_kernel(const float* __restrict__ feats, ushort* __restrict__ fb,
                            float* __restrict__ sq, int* __restrict__ cnt_g) {
    const int row  = blockIdx.x * 4 + (threadIdx.x >> 6);
    const int lane = threadIdx.x & 63;
    const float4 v = *reinterpret_cast<const float4*>(feats + (size_t)row * DIM + lane * 4);
    ushort4 b; b.x = f2bf(v.x); b.y = f2bf(v.y); b.z = f2bf(v.z); b.w = f2bf(v.w);
    *reinterpret_cast<ushort4*>(fb + (size_t)row * DIM + lane * 4) = b;
    float p = v.x * v.x + v.y * v.y + v.z * v.z + v.w * v.w;
#pragma unroll
    for (int off = 32; off > 0; off >>= 1) p += __shfl_down(p, off, 64);
    if (lane == 0) { sq[row] = p; cnt_g[row] = 0; }
}

// ---------------- K1b: deterministic stats (mu, var) ----------------
__global__ void stats_kernel(const float* __restrict__ sq, float* __restrict__ musig) {
    __shared__ double s0s[16], s1s[16];
    const int t = threadIdx.x, lane = t & 63, w = t >> 6;
    double s0 = 0.0, s1 = 0.0;
    for (int r = t; r < NPTS; r += 1024) {
        const double v = (double)sq[r];
        s0 += v; s1 += v * v;
    }
#pragma unroll
    for (int off = 32; off > 0; off >>= 1) {
        s0 += __shfl_down(s0, off, 64);
        s1 += __shfl_down(s1, off, 64);
    }
    if (lane == 0) { s0s[w] = s0; s1s[w] = s1; }
    __syncthreads();
    if (t == 0) {
        double a0 = 0.0, a1 = 0.0;
#pragma unroll
        for (int q = 0; q < 16; ++q) { a0 += s0s[q]; a1 += s1s[q]; }
        const double mu = a0 / NPTS;
        const double var = a1 / NPTS - mu * mu;
        musig[0] = (float)mu;
        musig[1] = (float)fmax(var, 1.0);
    }
}

// ---------------- K2: MFMA GEMM + fused threshold select ----------------
// 512 thr = 8 waves. Block: 64 rows (A resident in regs) x one 4096-col J-half.
__global__ __launch_bounds__(512, 1) void gemm_select_kernel(
    const ushort* __restrict__ fb, const float* __restrict__ sq,
    const float* __restrict__ musig, int* __restrict__ cand, int* __restrict__ cnt_g) {
    __shared__ ushort Bs[2][256 * 64];   // 2 x 32 KB [buf][col][k] swizzled
    __shared__ int    cbuf[64][LCAP];    // 32 KB
    __shared__ float  Ts[64], sqi_s[64];
    __shared__ int    cnt[64];
    __shared__ int    base_s[64], n_s[64];

    const int tid = threadIdx.x;
    const int w   = tid >> 6;
    const int l   = tid & 63;
    const int l15 = l & 15, lg = l >> 4;
    const int row0  = (blockIdx.x >> 1) * 64;
    const int Jbase = (blockIdx.x & 1) * 4096;

    if (tid < 64) {
        const float mu  = musig[0];
        const float var = musig[1];
        const float qi  = sq[row0 + tid];
        sqi_s[tid] = qi;
        Ts[tid]    = qi + mu + ZTH * sqrtf(var + 4.f * qi);
        cnt[tid]   = 0;
    }

    bf16x8 a[4][8];
#pragma unroll
    for (int mf = 0; mf < 4; ++mf) {
        const ushort* ap = fb + (size_t)(row0 + mf * 16 + l15) * DIM + lg * 8;
#pragma unroll
        for (int ks = 0; ks < 8; ++ks)
            a[mf][ks] = *reinterpret_cast<const bf16x8*>(ap + ks * 32);
    }

    {   // prologue: stage chunk 0
        const int kslot = tid & 7;
#pragma unroll
        for (int p = 0; p < 4; ++p) {
            const int col = (tid >> 3) + p * 64;
            const bf16x8 v = *reinterpret_cast<const bf16x8*>(
                fb + (size_t)(Jbase + col) * DIM + kslot * 8);
            const int byt = col * 128 + ((kslot * 16) ^ ((col & 7) << 4));
            *reinterpret_cast<bf16x8*>(reinterpret_cast<char*>(Bs[0]) + byt) = v;
        }
    }

    f32x4 acc[4][2];
#pragma unroll
    for (int mf = 0; mf < 4; ++mf) { acc[mf][0] = (f32x4){0,0,0,0}; acc[mf][1] = (f32x4){0,0,0,0}; }

    for (int tile = 0; tile < 16; ++tile) {
#pragma unroll
        for (int kc4 = 0; kc4 < 4; ++kc4) {
            __syncthreads();
            bf16x8 st[4];
            const int cnext = tile * 4 + kc4 + 1;
            const bool do_stage = (cnext < 64);
            if (do_stage) {
                const int Jn  = Jbase + (cnext >> 2) * 256;
                const int kcn = ((kc4 + 1) & 3) * 64;
                const int kslot = tid & 7;
#pragma unroll
                for (int p = 0; p < 4; ++p) {
                    const int col = (tid >> 3) + p * 64;
                    st[p] = *reinterpret_cast<const bf16x8*>(
                        fb + (size_t)(Jn + col) * DIM + kcn + kslot * 8);
                }
            }
            {
                const char* Bb = reinterpret_cast<const char*>(Bs[kc4 & 1]);
#pragma unroll
                for (int kk = 0; kk < 2; ++kk) {
                    const int col0 = w * 32 + l15;
                    const int col1 = w * 32 + 16 + l15;
                    const bf16x8 b0 = *reinterpret_cast<const bf16x8*>(
                        Bb + col0 * 128 + ((kk * 64 + lg * 16) ^ ((col0 & 7) << 4)));
                    const bf16x8 b1 = *reinterpret_cast<const bf16x8*>(
                        Bb + col1 * 128 + ((kk * 64 + lg * 16) ^ ((col1 & 7) << 4)));
#pragma unroll
                    for (int mf = 0; mf < 4; ++mf) {
                        acc[mf][0] = __builtin_amdgcn_mfma_f32_16x16x32_bf16(
                            a[mf][kc4 * 2 + kk], b0, acc[mf][0], 0, 0, 0);
                        acc[mf][1] = __builtin_amdgcn_mfma_f32_16x16x32_bf16(
                            a[mf][kc4 * 2 + kk], b1, acc[mf][1], 0, 0, 0);
                    }
                }
            }
            if (do_stage) {
                const int kslot = tid & 7;
                char* Bn = reinterpret_cast<char*>(Bs[(kc4 + 1) & 1]);
#pragma unroll
                for (int p = 0; p < 4; ++p) {
                    const int col = (tid >> 3) + p * 64;
                    const int byt = col * 128 + ((kslot * 16) ^ ((col & 7) << 4));
                    *reinterpret_cast<bf16x8*>(Bn + byt) = st[p];
                }
            }
        }
        // ---- per-J-tile epilogue: threshold select ----
        const int Jt = Jbase + tile * 256;
        const float sqc0 = sq[Jt + w * 32 + l15];
        const float sqc1 = sq[Jt + w * 32 + 16 + l15];
#pragma unroll
        for (int mf = 0; mf < 4; ++mf)
#pragma unroll
            for (int r = 0; r < 4; ++r) {
                const int row = mf * 16 + lg * 4 + r;
                const float si = sqi_s[row], tt = Ts[row];
                const float k0 = si + sqc0 - 2.f * acc[mf][0][r];
                if (k0 < tt) {
                    const int pos = atomicAdd(&cnt[row], 1);
                    if (pos < LCAP) cbuf[row][pos] = Jt + w * 32 + l15;
                }
                const float k1 = si + sqc1 - 2.f * acc[mf][1][r];
                if (k1 < tt) {
                    const int pos = atomicAdd(&cnt[row], 1);
                    if (pos < LCAP) cbuf[row][pos] = Jt + w * 32 + 16 + l15;
                }
            }
#pragma unroll
        for (int mf = 0; mf < 4; ++mf) { acc[mf][0] = (f32x4){0,0,0,0}; acc[mf][1] = (f32x4){0,0,0,0}; }
    }
    __syncthreads();
    if (tid < 64) {
        const int local = cnt[tid];
        const int n = min(local, LCAP);
        const int add = (local > LCAP) ? (n + (1 << 20)) : n;   // poison on overflow
        base_s[tid] = atomicAdd(&cnt_g[row0 + tid], add);
        n_s[tid] = n;
    }
    __syncthreads();
    for (int s = tid; s < 64 * LCAP; s += 512) {
        const int r = s >> 7, k2 = s & (LCAP - 1);
        if (k2 < n_s[r]) {
            const int b = base_s[r] + k2;
            if (b < CAP) cand[(size_t)(row0 + r) * CAP + b] = cbuf[r][k2];
        }
    }
}

// ---------------- K2b: detect + repair bad rows (expected none) ----------------
__global__ void fallback_kernel(const float* __restrict__ feats, const float* __restrict__ sq,
                                int* __restrict__ cand, int* __restrict__ cnt_g) {
    __shared__ float fi_s[DIM];
    __shared__ float keys[NPTS];
    __shared__ float rkey[4];
    __shared__ int   rid[4];
    const int t = threadIdx.x;
    for (int row = blockIdx.x; row < NPTS; row += gridDim.x) {
        const int v = cnt_g[row];
        if (v >= NSLOT && v <= CAP) continue;
        fi_s[t] = feats[(size_t)row * DIM + t];
        __syncthreads();
        const float sqi = sq[row];
        for (int p = 0; p < NPTS / 256; ++p) {
            const int jj = p * 256 + t;
            const float* fj = feats + (size_t)jj * DIM;
            float d = 0.f;
            for (int dq = 0; dq < DIM / 4; ++dq) {
                const float4 b4 = *reinterpret_cast<const float4*>(fj + dq * 4);
                const float4 a4 = *reinterpret_cast<const float4*>(&fi_s[dq * 4]);
                d = fmaf(a4.x, b4.x, fmaf(a4.y, b4.y, fmaf(a4.z, b4.z, fmaf(a4.w, b4.w, d))));
            }
            keys[jj] = sqi + sq[jj] - 2.f * d;
        }
        __syncthreads();
        for (int r = 0; r < 64; ++r) {
            float bk = INFINITY; int bj = 0x7fffffff;
            for (int p = 0; p < NPTS / 256; ++p) {
                const int jj = p * 256 + t;
                const float kv = keys[jj];
                if (kv < bk || (kv == bk && jj < bj)) { bk = kv; bj = jj; }
            }
#pragma unroll
            for (int off = 1; off <= 32; off <<= 1) {
                const float ok = __shfl_xor(bk, off, 64);
                const int   oj = __shfl_xor(bj, off, 64);
                if (ok < bk || (ok == bk && oj < bj)) { bk = ok; bj = oj; }
            }
            if ((t & 63) == 0) { rkey[t >> 6] = bk; rid[t >> 6] = bj; }
            __syncthreads();
            float fk = rkey[0]; int fj2 = rid[0];
#pragma unroll
            for (int q = 1; q < 4; ++q)
                if (rkey[q] < fk || (rkey[q] == fk && rid[q] < fj2)) { fk = rkey[q]; fj2 = rid[q]; }
            if (t == 0) { cand[(size_t)row * CAP + r] = fj2; keys[fj2] = INFINITY; }
            __syncthreads();
        }
        if (t == 0) cnt_g[row] = 64;
        __syncthreads();
    }
}

// ---------------- K3: fp64 refine (4 lanes/candidate) -> exact top-17 ----------------
__global__ __launch_bounds__(256) void refine_kernel(
    const float* __restrict__ feats, const int* __restrict__ cand,
    const int* __restrict__ cnt_g, int* __restrict__ fidx, float* __restrict__ fscr) {
    __shared__ float  fi_s[DIM];
    __shared__ double kdd[CAP];
    __shared__ float  kdot[CAP];
    __shared__ int    kidx[CAP];
    const int t = threadIdx.x, i = blockIdx.x;
    fi_s[t] = feats[(size_t)i * DIM + t];
    const int nc = min(cnt_g[i], CAP);
    __syncthreads();
    const int slot = t >> 2, chunk = t & 3;
#pragma unroll 1
    for (int b = 0; b < CAP / 64; ++b) {
        if (b * 64 >= nc) break;                       // uniform per block
        const int c = b * 64 + slot;
        const int j = (c < nc) ? cand[(size_t)i * CAP + c] : -1;
        double dd = 0.0, dot = 0.0;
        if (j >= 0) {
            const float* fj = feats + (size_t)j * DIM + chunk * 64;
            const float* fi = fi_s + chunk * 64;
#pragma unroll
            for (int q = 0; q < 16; ++q) {
                const float4 a4 = *reinterpret_cast<const float4*>(fi + q * 4);
                const float4 b4 = *reinterpret_cast<const float4*>(fj + q * 4);
                const double dx = (double)a4.x - b4.x, dy = (double)a4.y - b4.y;
                const double dz = (double)a4.z - b4.z, dw = (double)a4.w - b4.w;
                dd  += dx * dx + dy * dy + dz * dz + dw * dw;
                dot += (double)a4.x * b4.x + (double)a4.y * b4.y +
                       (double)a4.z * b4.z + (double)a4.w * b4.w;
            }
        }
        dd  += __shfl_xor(dd, 1, 64);  dd  += __shfl_xor(dd, 2, 64);
        dot += __shfl_xor(dot, 1, 64); dot += __shfl_xor(dot, 2, 64);
        if (chunk == 0) {
            kdd[c]  = (j >= 0) ? dd : 1e300;
            kdot[c] = (float)dot;
            kidx[c] = (j >= 0) ? j : 0x7fffffff;
        }
    }
    __syncthreads();
    if (t < 64) {                                      // wave 0: register tournament
        double kk[4]; int jj[4]; float ss[4];
#pragma unroll
        for (int p = 0; p < 4; ++p) {
            const int idx = p * 64 + t;
            if (idx < nc) { kk[p] = kdd[idx]; jj[p] = kidx[idx]; ss[p] = kdot[idx]; }
            else          { kk[p] = 1e300;    jj[p] = 0x7fffffff; ss[p] = 0.f; }
        }
        for (int r = 0; r < NSLOT; ++r) {
            double bk = kk[0]; int bj = jj[0]; float bs = ss[0];
#pragma unroll
            for (int p = 1; p < 4; ++p)
                if (kk[p] < bk || (kk[p] == bk && jj[p] < bj)) { bk = kk[p]; bj = jj[p]; bs = ss[p]; }
#pragma unroll
            for (int off = 1; off <= 32; off <<= 1) {
                const double ok = __shfl_xor(bk, off, 64);
                const int    oj = __shfl_xor(bj, off, 64);
                const float  os = __shfl_xor(bs, off, 64);
                if (ok < bk || (ok == bk && oj < bj)) { bk = ok; bj = oj; bs = os; }
            }
            if (t == 0) { fidx[(size_t)i * NSLOT + r] = bj; fscr[(size_t)i * NSLOT + r] = bs; }
#pragma unroll
            for (int p = 0; p < 4; ++p) if (jj[p] == bj) kk[p] = 1e300;
        }
    }
}

// ---------------- K4: mutual mask + sparse softmax + mix + normalize ----------------
__global__ void fcm_out_kernel(const float* __restrict__ feats,
                               const int* __restrict__ knn_idx,
                               const float* __restrict__ knn_scr,
                               float* __restrict__ out) {
    const int w    = threadIdx.x >> 6;
    const int lane = threadIdx.x & 63;
    const int i    = blockIdx.x * 4 + w;

    int jt = -1; float st = 0.f; bool valid = false;
    if (lane < NSLOT) {
        jt = knn_idx[(size_t)i * NSLOT + lane];
        st = knn_scr[(size_t)i * NSLOT + lane];
        if (jt != i) {
            const int* nb = knn_idx + (size_t)jt * NSLOT;
#pragma unroll
            for (int s = 0; s < NSLOT; ++s) valid |= (nb[s] == i);
        }
    }
    float val = valid ? st : -INFINITY;
#pragma unroll
    for (int off = 32; off > 0; off >>= 1) val = fmaxf(val, __shfl_xor(val, off, 64));
    const float m  = fmaxf(1.0f, val);
    const float wt = valid ? expf(st - m) : 0.f;
    float ws = wt;
#pragma unroll
    for (int off = 32; off > 0; off >>= 1) ws += __shfl_xor(ws, off, 64);
    const float wdiag = expf(1.0f - m);
    const float inv   = 1.0f / (ws + wdiag);

    const float4 fi = *reinterpret_cast<const float4*>(feats + (size_t)i * DIM + lane * 4);
    float ax = fi.x * wdiag, ay = fi.y * wdiag, az = fi.z * wdiag, aw = fi.w * wdiag;
    for (int t = 0; t < NSLOT; ++t) {
        const float wtt = __shfl(wt, t, 64);
        const int   jj  = __shfl(jt, t, 64);
        if (wtt > 0.f) {
            const float4 fj = *reinterpret_cast<const float4*>(feats + (size_t)jj * DIM + lane * 4);
            ax = fmaf(wtt, fj.x, ax); ay = fmaf(wtt, fj.y, ay);
            az = fmaf(wtt, fj.z, az); aw = fmaf(wtt, fj.w, aw);
        }
    }
    const float ox = fmaf(ax, inv, fi.x), oy = fmaf(ay, inv, fi.y);
    const float oz = fmaf(az, inv, fi.z), ow = fmaf(aw, inv, fi.w);
    float nn = ox * ox + oy * oy + oz * oz + ow * ow;
#pragma unroll
    for (int off = 32; off > 0; off >>= 1) nn += __shfl_xor(nn, off, 64);
    const float scl = 1.0f / fmaxf(sqrtf(nn), 1e-12f);
    float4 o; o.x = ox * scl; o.y = oy * scl; o.z = oz * scl; o.w = ow * scl;
    *reinterpret_cast<float4*>(out + (size_t)i * DIM + lane * 4) = o;
}

extern "C" void kernel_launch(void* const* d_in, const int* in_sizes, int n_in,
                              void* d_out, int out_size, void* d_ws, size_t ws_size,
                              hipStream_t stream) {
    (void)in_sizes; (void)n_in; (void)out_size; (void)ws_size;
    const float* feats = (const float*)d_in[0];
    float* out = (float*)d_out;
    char* ws = (char*)d_ws;
    size_t off = 0;
    float*  sq    = (float*) (ws + off); off += NPTS * 4;                 // 32 KB
    float*  musig = (float*) (ws + off); off += 128;
    ushort* fb    = (ushort*)(ws + off); off += (size_t)NPTS * DIM * 2;   // 4 MB
    int*    cand  = (int*)   (ws + off); off += (size_t)NPTS * CAP * 4;   // 8 MB
    int*    cnt_g = (int*)   (ws + off); off += NPTS * 4;
    int*    fidx  = (int*)   (ws + off); off += NPTS * NSLOT * 4;
    float*  fscr  = (float*) (ws + off); off += NPTS * NSLOT * 4;

    prep_kernel<<<NPTS / 4, 256, 0, stream>>>(feats, fb, sq, cnt_g);
    stats_kernel<<<1, 1024, 0, stream>>>(sq, musig);
    gemm_select_kernel<<<NPTS / 32, 512, 0, stream>>>(fb, sq, musig, cand, cnt_g);
    fallback_kernel<<<64, 256, 0, stream>>>(feats, sq, cand, cnt_g);
    refine_kernel<<<NPTS, 256, 0, stream>>>(feats, cand, cnt_g, fidx, fscr);
    fcm_out_kernel<<<NPTS / 4, 256, 0, stream>>>(feats, fidx, fscr, out);
}